// Round 8
// baseline (293.673 us; speedup 1.0000x reference)
//
#include <hip/hip_runtime.h>
#include <hip/hip_bf16.h>

typedef short bf16x8 __attribute__((ext_vector_type(8)));
typedef float f32x4 __attribute__((ext_vector_type(4)));
typedef unsigned short u16;

#define AS1 __attribute__((address_space(1)))
#define AS3 __attribute__((address_space(3)))

#define DIM     1024
#define INNER   512
#define HEADS   8
#define DHEAD   64
#define BATCH   4
#define NTOK    4096
#define NLAT    1024
#define M_X     (BATCH*NTOK)    // 16384
#define M_MED   (BATCH*NLAT)    // 4096
#define LN_EPS  1e-5f
#define QSCALE  (0.125f * 1.44269504f)   // 1/sqrt(64) * log2(e)

__device__ __forceinline__ float b2f(u16 h) {
    union { unsigned u; float f; } v; v.u = ((unsigned)h) << 16; return v.f;
}
__device__ __forceinline__ u16 f2b(float f) {
    union { float f; unsigned u; } v; v.f = f;
    unsigned r = v.u + 0x7fff + ((v.u >> 16) & 1);
    return (u16)(r >> 16);
}
// packed f32x2 -> bf16x2 (RNE), single instruction
__device__ __forceinline__ unsigned cvt_pk(float lo, float hi) {
    unsigned r;
    asm("v_cvt_pk_bf16_f32 %0, %1, %2" : "=v"(r) : "v"(lo), "v"(hi));
    return r;
}

// ---------------- dtype detection ----------------
__launch_bounds__(256)
__global__ void detect_kernel(const unsigned* __restrict__ xw, const unsigned* __restrict__ maskw,
                              unsigned* __restrict__ flags) {
    __shared__ int s_bad, s_byte;
    if (threadIdx.x == 0) { s_bad = 0; s_byte = 0; }
    __syncthreads();
    unsigned w = xw[threadIdx.x];
    int bad = 0;
    #pragma unroll
    for (int h = 0; h < 2; h++) {
        unsigned el = (h ? (w >> 16) : w) & 0xFFFFu;
        unsigned ef = (el >> 7) & 0xFFu;
        if (!((ef >= 64u && ef < 192u) || (el & 0x7FFFu) == 0u)) bad = 1;
    }
    if (bad) atomicOr(&s_bad, 1);
    for (int i = threadIdx.x; i < NLAT; i += 256)
        if (maskw[i] > 1u) { atomicOr(&s_byte, 1); break; }
    __syncthreads();
    if (threadIdx.x == 0) { flags[0] = s_bad ? 0u : 1u; flags[1] = s_byte ? 1u : 0u; }
}

// ---------------- fused prep ----------------
// LN is NOT materialized: q = inv*(x @ (g.Wq)) - inv*mu*(g@Wq) + beta@Wq  (fixup in GEMM epilogue)
// GEMMs read raw x / media (f32 reg-staged, bf16 direct). No xn / media_c buffers.
// region layout by blockIdx.x:
//   [0, 2048)      LN row stats only: stats[row] = (inv*QSCALE, inv*mu*QSCALE)
//   [2048, 2052)   mask scan: map[b][j] -> compact slot (-1 if masked), cnt[b]
//   [2052, 2564)   Wq^T scaled by g  (16 x 32)
//   [2564, 3588)   Wkv^T (32 x 32)
//   [3588, 4100)   Wout^T(32 x 16)
//   [4100, 4108)   G = g@Wq, B = (beta@Wq)*QSCALE   (8 blocks x 64 cols)
#define PREP_BLOCKS 4108

__device__ __forceinline__ void do_transpose(const void* in, u16* out, int R, int C,
                                             int bx, int by, bool bf, u16 (*t)[33],
                                             const void* gv) {
    int c0 = bx * 32, r0 = by * 32;
    int tid = threadIdx.x;
    int r = tid >> 3, cb = (tid & 7) * 4;
    size_t base = (size_t)(r0 + r) * C + c0 + cb;
    u16 e0, e1, e2, e3;
    if (bf) {
        ushort4 a = *(const ushort4*)((const u16*)in + base);
        if (gv) {
            float sc = b2f(((const u16*)gv)[r0 + r]);
            e0 = f2b(b2f(a.x) * sc); e1 = f2b(b2f(a.y) * sc);
            e2 = f2b(b2f(a.z) * sc); e3 = f2b(b2f(a.w) * sc);
        } else {
            e0 = a.x; e1 = a.y; e2 = a.z; e3 = a.w;
        }
    } else {
        float4 a = *(const float4*)((const float*)in + base);
        float sc = gv ? ((const float*)gv)[r0 + r] : 1.f;
        e0 = f2b(a.x * sc); e1 = f2b(a.y * sc); e2 = f2b(a.z * sc); e3 = f2b(a.w * sc);
    }
    t[r][cb] = e0; t[r][cb + 1] = e1; t[r][cb + 2] = e2; t[r][cb + 3] = e3;
    __syncthreads();
    ushort4 o;
    o.x = t[cb + 0][r]; o.y = t[cb + 1][r]; o.z = t[cb + 2][r]; o.w = t[cb + 3][r];
    *(ushort4*)(out + (size_t)(c0 + r) * R + r0 + cb) = o;
}

__launch_bounds__(256)
__global__ void prep_kernel(const void* __restrict__ x, const void* __restrict__ g,
                            const void* __restrict__ bt,
                            const void* __restrict__ mask, int* __restrict__ map,
                            int* __restrict__ cnt,
                            const void* __restrict__ Wq, u16* __restrict__ WqT,
                            const void* __restrict__ Wkv, u16* __restrict__ WkvT,
                            const void* __restrict__ Wout, u16* __restrict__ WoutT,
                            float2* __restrict__ stats, float* __restrict__ Gv,
                            float* __restrict__ Bv,
                            const unsigned* __restrict__ flags) {
    __shared__ int wsumI[4];
    __shared__ u16 t[32][33];
    __shared__ float rg[4][64], rb[4][64];
    bool bf = flags[0] != 0;
    int bid = blockIdx.x, tid = threadIdx.x;

    if (bid < 2048) {                        // ---- LN row stats, two rows per wave ----
        int w = tid >> 6, lane = tid & 63;
        int row0 = (bid << 3) + (w << 1);
        float s[2] = {0.f, 0.f}, s2[2] = {0.f, 0.f};
        if (bf) {
            const u16* xr = (const u16*)x + (size_t)row0 * DIM;
            #pragma unroll
            for (int rr = 0; rr < 2; rr++)
                #pragma unroll
                for (int i = 0; i < 2; i++) {
                    bf16x8 a = *(const bf16x8*)(xr + (size_t)rr * DIM + (lane + 64 * i) * 8);
                    #pragma unroll
                    for (int j = 0; j < 8; j++) {
                        float f = b2f((u16)a[j]);
                        s[rr] += f; s2[rr] += f * f;
                    }
                }
        } else {
            const float* xr = (const float*)x + (size_t)row0 * DIM;
            #pragma unroll
            for (int rr = 0; rr < 2; rr++)
                #pragma unroll
                for (int i = 0; i < 4; i++) {
                    float4 a = *(const float4*)(xr + (size_t)rr * DIM + (lane + 64 * i) * 4);
                    s[rr] += a.x + a.y + a.z + a.w;
                    s2[rr] += a.x * a.x + a.y * a.y + a.z * a.z + a.w * a.w;
                }
        }
        #pragma unroll
        for (int m = 1; m < 64; m <<= 1) {
            #pragma unroll
            for (int rr = 0; rr < 2; rr++) {
                s[rr] += __shfl_xor(s[rr], m);
                s2[rr] += __shfl_xor(s2[rr], m);
            }
        }
        #pragma unroll
        for (int rr = 0; rr < 2; rr++) {
            float mu = s[rr] * (1.f / DIM);
            float var = s2[rr] * (1.f / DIM) - mu * mu;
            float inv = rsqrtf(fmaxf(var, 0.f) + LN_EPS);
            if (lane == 0) stats[row0 + rr] = make_float2(inv * QSCALE, inv * mu * QSCALE);
        }
    } else if (bid < 2052) {                 // ---- mask scan (one block per batch) ----
        int b = bid - 2048;
        bool bytes = flags[1] != 0;
        int v[4];
        if (bytes) {
            unsigned wd = ((const unsigned*)mask)[b * 256 + tid];
            #pragma unroll
            for (int i = 0; i < 4; i++) v[i] = ((wd >> (8 * i)) & 0xFFu) ? 1 : 0;
        } else {
            int4 m4 = ((const int4*)mask)[b * 256 + tid];
            v[0] = m4.x != 0; v[1] = m4.y != 0; v[2] = m4.z != 0; v[3] = m4.w != 0;
        }
        int tsum = v[0] + v[1] + v[2] + v[3];
        int lane = tid & 63, w = tid >> 6;
        int incl = tsum;
        #pragma unroll
        for (int off = 1; off < 64; off <<= 1) {
            int tt = __shfl_up(incl, off);
            if (lane >= off) incl += tt;
        }
        if (lane == 63) wsumI[w] = incl;
        __syncthreads();
        int base = 0;
        for (int k = 0; k < w; k++) base += wsumI[k];
        int slot = base + incl - tsum;
        int gbase = b * NLAT + tid * 4;
        #pragma unroll
        for (int i = 0; i < 4; i++) map[gbase + i] = v[i] ? slot++ : -1;
        if (tid == 0) cnt[b] = wsumI[0] + wsumI[1] + wsumI[2] + wsumI[3];
    } else if (bid < 2564) {                 // ---- Wq^T scaled by g ----
        int idx = bid - 2052;
        do_transpose(Wq, WqT, DIM, INNER, idx & 15, idx >> 4, bf, t, g);
    } else if (bid < 3588) {                 // ---- Wkv^T ----
        int idx = bid - 2564;
        do_transpose(Wkv, WkvT, DIM, DIM, idx & 31, idx >> 5, bf, t, nullptr);
    } else if (bid < 4100) {                 // ---- Wout^T ----
        int idx = bid - 3588;
        do_transpose(Wout, WoutT, INNER, DIM, idx & 31, idx >> 5, bf, t, nullptr);
    } else {                                 // ---- G = g@Wq, B = (beta@Wq)*QSCALE ----
        int idx = bid - 4100;                // 0..7, 64 cols each
        int col = idx * 64 + (tid & 63), kq = tid >> 6;
        float ag = 0.f, ab = 0.f;
        if (bf) {
            const u16* W = (const u16*)Wq;
            const u16* gg = (const u16*)g;
            const u16* bb = (const u16*)bt;
            for (int k = kq * 256; k < kq * 256 + 256; k += 4) {
                #pragma unroll
                for (int u = 0; u < 4; u++) {
                    float wv = b2f(W[(size_t)(k + u) * INNER + col]);
                    ag += b2f(gg[k + u]) * wv;
                    ab += b2f(bb[k + u]) * wv;
                }
            }
        } else {
            const float* W = (const float*)Wq;
            const float* gg = (const float*)g;
            const float* bb = (const float*)bt;
            for (int k = kq * 256; k < kq * 256 + 256; k += 4) {
                #pragma unroll
                for (int u = 0; u < 4; u++) {
                    float wv = W[(size_t)(k + u) * INNER + col];
                    ag += gg[k + u] * wv;
                    ab += bb[k + u] * wv;
                }
            }
        }
        rg[kq][tid & 63] = ag; rb[kq][tid & 63] = ab;
        __syncthreads();
        if (kq == 0) {
            int c = tid & 63;
            Gv[col] = rg[0][c] + rg[1][c] + rg[2][c] + rg[3][c];
            Bv[col] = (rb[0][c] + rb[1][c] + rb[2][c] + rb[3][c]) * QSCALE;
        }
    }
}

// ---------------- GEMM 128x128 body, BK=64, flash-style XOR swizzle ----------------
// LDS tile [128 rows][8 groups of 8 u16]; physical group p at row r holds logical p ^ (r&7).
// AF32: A is f32, reg-staged (load f32 -> cvt_pk -> swizzled ds_write). B always bf16 gload_lds.
// mode 0: Q with LN fixup epilogue  val = st.x*acc - st.y*G[col] + B[col]
// mode 1: KV scatter via map        mode 2: plain (dtype by outbf), scaled
template<bool AF32>
__device__ __forceinline__ void gemm_body(const void* __restrict__ Ap, const u16* __restrict__ Bt,
                                          u16* __restrict__ C, float* __restrict__ Cf,
                                          int Ndim, int K, float scale, int mode,
                                          u16* __restrict__ vT, const int* __restrict__ map,
                                          bool outbf, int n0, int m0, u16* As, u16* Bs,
                                          const float2* __restrict__ stats,
                                          const float* __restrict__ Gv,
                                          const float* __restrict__ Bv) {
    int tid = threadIdx.x;
    int w = tid >> 6, lane = tid & 63, quad = lane >> 4, l15 = lane & 15;
    int wm = (w >> 1) * 64, wn = (w & 1) * 64;
    f32x4 acc[4][4] = {};
    for (int k0 = 0; k0 < K; k0 += 64) {
        __syncthreads();
        #pragma unroll
        for (int i = 0; i < 4; i++) {                 // B staging: 4 gload_lds
            int slot = i * 256 + tid;                 // slot = row*8 + physgrp
            int row = slot >> 3;
            int lg = (slot & 7) ^ (row & 7);          // logical source group
            int wbase = (i * 256 + (tid & 192)) * 8;  // wave-uniform LDS dest (u16)
            __builtin_amdgcn_global_load_lds(
                (const AS1 void*)(Bt + (size_t)(n0 + row) * K + k0 + lg * 8),
                (AS3 void*)(Bs + wbase), 16, 0, 0);
        }
        if constexpr (AF32) {                         // A staging: f32 -> bf16 reg-staged
            int row = tid >> 1, ch = (tid & 1) * 32;
            const float* src = (const float*)Ap + (size_t)(m0 + row) * K + k0 + ch;
            float4 a[8];
            #pragma unroll
            for (int i = 0; i < 8; i++) a[i] = *(const float4*)(src + i * 4);
            #pragma unroll
            for (int gi = 0; gi < 4; gi++) {
                int lg = (ch >> 3) + gi;
                int ph = lg ^ (row & 7);
                uint4 wv;
                wv.x = cvt_pk(a[gi * 2].x, a[gi * 2].y);
                wv.y = cvt_pk(a[gi * 2].z, a[gi * 2].w);
                wv.z = cvt_pk(a[gi * 2 + 1].x, a[gi * 2 + 1].y);
                wv.w = cvt_pk(a[gi * 2 + 1].z, a[gi * 2 + 1].w);
                *(uint4*)&As[row * 64 + ph * 8] = wv;
            }
        } else {                                      // A staging: bf16 gload_lds
            #pragma unroll
            for (int i = 0; i < 4; i++) {
                int slot = i * 256 + tid;
                int row = slot >> 3;
                int lg = (slot & 7) ^ (row & 7);
                int wbase = (i * 256 + (tid & 192)) * 8;
                __builtin_amdgcn_global_load_lds(
                    (const AS1 void*)((const u16*)Ap + (size_t)(m0 + row) * K + k0 + lg * 8),
                    (AS3 void*)(As + wbase), 16, 0, 0);
            }
        }
        __syncthreads();
        #pragma unroll
        for (int h = 0; h < 2; h++) {                 // two K=32 halves of the BK=64 tile
            bf16x8 af[4], bfr[4];
            #pragma unroll
            for (int i = 0; i < 4; i++) {
                int R = wm + i * 16 + l15;
                af[i] = *(bf16x8*)&As[R * 64 + (((quad + h * 4) ^ (R & 7)) * 8)];
            }
            #pragma unroll
            for (int j = 0; j < 4; j++) {
                int R = wn + j * 16 + l15;
                bfr[j] = *(bf16x8*)&Bs[R * 64 + (((quad + h * 4) ^ (R & 7)) * 8)];
            }
            #pragma unroll
            for (int i = 0; i < 4; i++)
                #pragma unroll
                for (int j = 0; j < 4; j++)
                    acc[i][j] = __builtin_amdgcn_mfma_f32_16x16x32_bf16(af[i], bfr[j], acc[i][j], 0, 0, 0);
        }
    }
    #pragma unroll
    for (int i = 0; i < 4; i++)
        #pragma unroll
        for (int j = 0; j < 4; j++)
            #pragma unroll
            for (int r = 0; r < 4; r++) {
                int row = m0 + wm + i * 16 + quad * 4 + r;
                int col = n0 + wn + j * 16 + l15;
                if (mode == 0) {
                    float2 st = stats[row];
                    float val = st.x * acc[i][j][r] - st.y * Gv[col] + Bv[col];
                    C[(size_t)row * Ndim + col] = f2b(val);
                } else if (mode == 1) {
                    float val = acc[i][j][r];
                    int b = row >> 10, jj = row & 1023;
                    int slot = map[(b << 10) + jj];
                    if (slot >= 0) {
                        if (col < INNER) {
                            C[((size_t)(b << 10) + slot) * INNER + col] = f2b(val);
                        } else {
                            int c = col - INNER;
                            int h = c >> 6, d = c & 63;
                            vT[(((size_t)(b * HEADS + h) * 64 + d) << 10) + slot] = f2b(val);
                        }
                    }
                } else {
                    float val = acc[i][j][r] * scale;
                    if (outbf) C[(size_t)row * Ndim + col] = f2b(val);
                    else       Cf[(size_t)row * Ndim + col] = val;
                }
            }
}

__launch_bounds__(256, 3)
__global__ void gemm128(const u16* __restrict__ A, const u16* __restrict__ Bt,
                        u16* __restrict__ C, float* __restrict__ Cf, int Ndim, int K,
                        float scale, int mode, u16* __restrict__ vT,
                        const int* __restrict__ map,
                        const unsigned* __restrict__ flags) {
    __shared__ __align__(16) u16 As[128 * 64];
    __shared__ __align__(16) u16 Bs[128 * 64];
    bool outbf = (mode != 2) || (flags[0] != 0);
    gemm_body<false>(A, Bt, C, Cf, Ndim, K, scale, mode, vT, map, outbf,
                     blockIdx.x * 128, blockIdx.y * 128, As, Bs,
                     (const float2*)nullptr, (const float*)nullptr, (const float*)nullptr);
}

// ---- merged Q-GEMM (512 blocks, LN-fused, raw x) + KV-GEMM (256 blocks, raw media) ----
__launch_bounds__(256, 3)
__global__ void gemm_qkv(const void* __restrict__ x, const u16* __restrict__ WqT,
                         u16* __restrict__ qb,
                         const void* __restrict__ media, const u16* __restrict__ WkvT,
                         u16* __restrict__ Kb, u16* __restrict__ vT,
                         const int* __restrict__ map,
                         const float2* __restrict__ stats, const float* __restrict__ Gv,
                         const float* __restrict__ Bv,
                         const unsigned* __restrict__ flags) {
    __shared__ __align__(16) u16 As[128 * 64];
    __shared__ __align__(16) u16 Bs[128 * 64];
    bool bf = flags[0] != 0;
    int bid = blockIdx.x;
    if (bid < 512) {
        int n0 = (bid & 3) * 128, m0 = (bid >> 2) * 128;
        if (bf)
            gemm_body<false>(x, WqT, qb, (float*)nullptr, INNER, DIM, 1.0f, 0,
                             (u16*)nullptr, (int*)nullptr, true, n0, m0, As, Bs, stats, Gv, Bv);
        else
            gemm_body<true>(x, WqT, qb, (float*)nullptr, INNER, DIM, 1.0f, 0,
                            (u16*)nullptr, (int*)nullptr, true, n0, m0, As, Bs, stats, Gv, Bv);
    } else {
        int id = bid - 512;
        int n0 = (id & 7) * 128, m0 = (id >> 3) * 128;
        if (bf)
            gemm_body<false>(media, WkvT, Kb, (float*)nullptr, DIM, DIM, 1.0f, 1,
                             vT, map, true, n0, m0, As, Bs,
                             (const float2*)nullptr, (const float*)nullptr, (const float*)nullptr);
        else
            gemm_body<true>(media, WkvT, Kb, (float*)nullptr, DIM, DIM, 1.0f, 1,
                            vT, map, true, n0, m0, As, Bs,
                            (const float2*)nullptr, (const float*)nullptr, (const float*)nullptr);
    }
}

// ---------------- Flash attention v6: swapped QK^T, packed P, exp2 ----------------
// Q comes pre-scaled by 1/sqrt(64) * log2(e), so P = exp2(S).
// Swapped QK^T: S = mfma(K, Q) => lane holds P[q=l15][k = c*16 + quad*4 + r]
// (4 consecutive k per lane -> cvt_pk + ds_write_b64 packing, no cross-lane).
__launch_bounds__(256, 6)
__global__ void flash_kernel(const u16* __restrict__ q, const u16* __restrict__ Kc,
                             const u16* __restrict__ vTc, const int* __restrict__ cntp,
                             u16* __restrict__ attn_out) {
    __shared__ __align__(16) u16 Ks[64 * 64];        // physical colgroup p = logical ^ (row&7)
    __shared__ __align__(16) u16 Vts[64 * 64];
    __shared__ __align__(16) u16 Ps[4][16 * 68];     // per-wave, q-major stride 68
    int bh = blockIdx.x >> 6;
    int qt = blockIdx.x & 63;
    int b = bh >> 3, h = bh & 7;
    int tid = threadIdx.x, w = tid >> 6, lane = tid & 63, quad = lane >> 4, l15 = lane & 15;
    int qrow0 = qt * 64 + w * 16;
    int cnt = cntp[b];

    size_t qbase = ((size_t)(b * NTOK) + qrow0 + l15) * INNER + h * 64;
    bf16x8 qf[2];
    qf[0] = *(const bf16x8*)(q + qbase + quad * 8);
    qf[1] = *(const bf16x8*)(q + qbase + 32 + quad * 8);

    f32x4 Oacc[4] = {};
    float lsum = 0.f;
    int ld_row = lane >> 3;
    int ld_col = ((lane & 7) ^ ld_row) * 8;          // swizzled source colgroup

    for (int jt = 0; jt < cnt; jt += 64) {
        __syncthreads();
        #pragma unroll
        for (int i = 0; i < 2; i++) {
            int seg = w * 2 + i;                     // 8 segments = 64 rows
            int j = jt + seg * 8 + ld_row;
            __builtin_amdgcn_global_load_lds(
                (const AS1 void*)(Kc + ((size_t)(b * NLAT) + j) * INNER + h * 64 + ld_col),
                (AS3 void*)(Ks + seg * 512), 16, 0, 0);
            int d = seg * 8 + ld_row;
            __builtin_amdgcn_global_load_lds(
                (const AS1 void*)(vTc + (((size_t)(b * HEADS + h) * 64 + d) << 10) + jt + ld_col),
                (AS3 void*)(Vts + seg * 512), 16, 0, 0);
        }
        __syncthreads();

        int sw0 = (quad ^ (l15 & 7)) * 8;            // logical groups quad / quad+4
        int sw1 = ((quad + 4) ^ (l15 & 7)) * 8;
        f32x4 S[4];
        #pragma unroll
        for (int c = 0; c < 4; c++) {
            bf16x8 kf0 = *(bf16x8*)&Ks[(c * 16 + l15) * 64 + sw0];
            bf16x8 kf1 = *(bf16x8*)&Ks[(c * 16 + l15) * 64 + sw1];
            f32x4 s = {};
            s = __builtin_amdgcn_mfma_f32_16x16x32_bf16(kf0, qf[0], s, 0, 0, 0);   // swapped
            s = __builtin_amdgcn_mfma_f32_16x16x32_bf16(kf1, qf[1], s, 0, 0, 0);
            S[c] = s;
        }
        if (jt + 64 <= cnt) {                        // fast path: full tile, no masking
            #pragma unroll
            for (int c = 0; c < 4; c++) {
                float p0 = exp2f(fminf(S[c][0], 115.4f));
                float p1 = exp2f(fminf(S[c][1], 115.4f));
                float p2 = exp2f(fminf(S[c][2], 115.4f));
                float p3 = exp2f(fminf(S[c][3], 115.4f));
                lsum += (p0 + p1) + (p2 + p3);
                uint2 pw = {cvt_pk(p0, p1), cvt_pk(p2, p3)};
                *(uint2*)&Ps[w][l15 * 68 + c * 16 + quad * 4] = pw;
            }
        } else {                                     // tail tile: mask k >= cnt
            #pragma unroll
            for (int c = 0; c < 4; c++) {
                int kbase = jt + c * 16 + quad * 4;
                float p[4];
                #pragma unroll
                for (int r = 0; r < 4; r++) {
                    bool valid = (kbase + r) < cnt;
                    p[r] = valid ? exp2f(fminf(S[c][r], 115.4f)) : 0.f;
                    lsum += p[r];
                }
                uint2 pw = {cvt_pk(p[0], p[1]), cvt_pk(p[2], p[3])};
                *(uint2*)&Ps[w][l15 * 68 + c * 16 + quad * 4] = pw;
            }
        }
        asm volatile("s_waitcnt lgkmcnt(0)" ::: "memory");   // Ps[w] is wave-private
        bf16x8 pf0 = *(bf16x8*)&Ps[w][l15 * 68 + quad * 8];
        bf16x8 pf1 = *(bf16x8*)&Ps[w][l15 * 68 + 32 + quad * 8];
        #pragma unroll
        for (int dt = 0; dt < 4; dt++) {
            bf16x8 vf0 = *(bf16x8*)&Vts[(dt * 16 + l15) * 64 + sw0];
            bf16x8 vf1 = *(bf16x8*)&Vts[(dt * 16 + l15) * 64 + sw1];
            Oacc[dt] = __builtin_amdgcn_mfma_f32_16x16x32_bf16(pf0, vf0, Oacc[dt], 0, 0, 0);
            Oacc[dt] = __builtin_amdgcn_mfma_f32_16x16x32_bf16(pf1, vf1, Oacc[dt], 0, 0, 0);
        }
    }
    // row-sum: each lane has partial for q=l15; reduce across quads, then fetch per output row
    lsum += __shfl_xor(lsum, 16);
    lsum += __shfl_xor(lsum, 32);
    #pragma unroll
    for (int r = 0; r < 4; r++) {
        float l = __shfl(lsum, quad * 4 + r);        // row-sum for q row quad*4+r
        float invl = (l > 0.f) ? (1.f / l) : 0.f;
        #pragma unroll
        for (int dt = 0; dt < 4; dt++) {
            int row = qrow0 + quad * 4 + r;
            int col = h * 64 + dt * 16 + l15;
            attn_out[(size_t)(b * NTOK + row) * INNER + col] = f2b(Oacc[dt][r] * invl);
        }
    }
}

extern "C" void kernel_launch(void* const* d_in, const int* in_sizes, int n_in,
                              void* d_out, int out_size, void* d_ws, size_t ws_size,
                              hipStream_t stream) {
    const void* x     = d_in[0];
    const void* media = d_in[1];
    const void* mask  = d_in[2];
    const void* g     = d_in[3];
    const void* beta  = d_in[4];
    const void* Wq    = d_in[5];
    const void* Wkv   = d_in[6];
    const void* Wout  = d_in[7];

    char* ws = (char*)d_ws;
    unsigned* flags = (unsigned*)ws;   ws += 256;
    int* map_c  = (int*)ws;            ws += (size_t)M_MED * 4;
    int* cnt_c  = (int*)ws;            ws += 256;
    float2* stats = (float2*)ws;       ws += (size_t)M_X * 8;
    float* Gv   = (float*)ws;          ws += INNER * 4;
    float* Bv   = (float*)ws;          ws += INNER * 4;
    u16* qb    = (u16*)ws;             ws += (size_t)M_X * INNER * 2;
    u16* Kb    = (u16*)ws;             ws += (size_t)M_MED * INNER * 2;
    u16* vTb   = (u16*)ws;             ws += (size_t)M_MED * INNER * 2;
    u16* ao    = (u16*)ws;             ws += (size_t)M_X * INNER * 2;
    u16* WqT   = (u16*)ws;             ws += (size_t)DIM * INNER * 2;
    u16* WkvT  = (u16*)ws;             ws += (size_t)DIM * DIM * 2;
    u16* WoutT = (u16*)ws;             ws += (size_t)INNER * DIM * 2;

    detect_kernel<<<1, 256, 0, stream>>>((const unsigned*)x, (const unsigned*)mask, flags);
    prep_kernel<<<PREP_BLOCKS, 256, 0, stream>>>(x, g, beta, mask, map_c, cnt_c,
                                                 Wq, WqT, Wkv, WkvT, Wout, WoutT,
                                                 stats, Gv, Bv, flags);
    // merged: q = LN-fused GEMM on raw x   AND   kv = raw media @ Wkv (scatter K / V^T)
    gemm_qkv<<<dim3(768), 256, 0, stream>>>(x, WqT, qb, media, WkvT, Kb, vTb,
                                            map_c, stats, Gv, Bv, flags);
    // masked flash attention over compacted KV
    flash_kernel<<<dim3(32 * 64), 256, 0, stream>>>(qb, Kb, vTb, cnt_c, ao);
    // out = attn_out @ Wout (dtype follows flags)
    gemm128<<<dim3(DIM / 128, M_X / 128), 256, 0, stream>>>(ao, WoutT, (u16*)d_out, (float*)d_out, DIM, INNER,
                                                            1.0f, 2, (u16*)nullptr, (int*)nullptr, flags);
}

// Round 9
// 273.277 us; speedup vs baseline: 1.0746x; 1.0746x over previous
//
#include <hip/hip_runtime.h>
#include <hip/hip_bf16.h>

typedef short bf16x8 __attribute__((ext_vector_type(8)));
typedef float f32x4 __attribute__((ext_vector_type(4)));
typedef unsigned short u16;

#define AS1 __attribute__((address_space(1)))
#define AS3 __attribute__((address_space(3)))

#define DIM     1024
#define INNER   512
#define HEADS   8
#define DHEAD   64
#define BATCH   4
#define NTOK    4096
#define NLAT    1024
#define M_X     (BATCH*NTOK)    // 16384
#define M_MED   (BATCH*NLAT)    // 4096
#define LN_EPS  1e-5f

__device__ __forceinline__ float b2f(u16 h) {
    union { unsigned u; float f; } v; v.u = ((unsigned)h) << 16; return v.f;
}
__device__ __forceinline__ u16 f2b(float f) {
    union { float f; unsigned u; } v; v.f = f;
    unsigned r = v.u + 0x7fff + ((v.u >> 16) & 1);
    return (u16)(r >> 16);
}
// packed f32x2 -> bf16x2 (RNE), single instruction
__device__ __forceinline__ unsigned cvt_pk(float lo, float hi) {
    unsigned r;
    asm("v_cvt_pk_bf16_f32 %0, %1, %2" : "=v"(r) : "v"(lo), "v"(hi));
    return r;
}

// ---------------- dtype detection ----------------
__launch_bounds__(256)
__global__ void detect_kernel(const unsigned* __restrict__ xw, const unsigned* __restrict__ maskw,
                              unsigned* __restrict__ flags) {
    __shared__ int s_bad, s_byte;
    if (threadIdx.x == 0) { s_bad = 0; s_byte = 0; }
    __syncthreads();
    unsigned w = xw[threadIdx.x];
    int bad = 0;
    #pragma unroll
    for (int h = 0; h < 2; h++) {
        unsigned el = (h ? (w >> 16) : w) & 0xFFFFu;
        unsigned ef = (el >> 7) & 0xFFu;
        if (!((ef >= 64u && ef < 192u) || (el & 0x7FFFu) == 0u)) bad = 1;
    }
    if (bad) atomicOr(&s_bad, 1);
    for (int i = threadIdx.x; i < NLAT; i += 256)
        if (maskw[i] > 1u) { atomicOr(&s_byte, 1); break; }
    __syncthreads();
    if (threadIdx.x == 0) { flags[0] = s_bad ? 0u : 1u; flags[1] = s_byte ? 1u : 0u; }
}

// ---------------- fused prep: LN + media convert + mask scan + 3 weight transposes ----------------
// region layout by blockIdx.x:
//   [0, 2048)      LN rows, 2 rows per wave (8 rows per block, barrier-free)
//   [2048, 4096)   media -> bf16
//   [4096, 4100)   mask scan: map[b][j] -> compact slot (-1 if masked), cnt[b]
//   [4100, 4612)   Wq^T  (16 x 32)
//   [4612, 5636)   Wkv^T (32 x 32)
//   [5636, 6148)   Wout^T(32 x 16)
#define PREP_BLOCKS 6148

__device__ __forceinline__ void do_transpose(const void* in, u16* out, int R, int C,
                                             int bx, int by, bool bf, u16 (*t)[33]) {
    int c0 = bx * 32, r0 = by * 32;
    int tid = threadIdx.x;
    int r = tid >> 3, cb = (tid & 7) * 4;
    size_t base = (size_t)(r0 + r) * C + c0 + cb;
    u16 e0, e1, e2, e3;
    if (bf) {
        ushort4 a = *(const ushort4*)((const u16*)in + base);
        e0 = a.x; e1 = a.y; e2 = a.z; e3 = a.w;
    } else {
        float4 a = *(const float4*)((const float*)in + base);
        e0 = f2b(a.x); e1 = f2b(a.y); e2 = f2b(a.z); e3 = f2b(a.w);
    }
    t[r][cb] = e0; t[r][cb + 1] = e1; t[r][cb + 2] = e2; t[r][cb + 3] = e3;
    __syncthreads();
    ushort4 o;
    o.x = t[cb + 0][r]; o.y = t[cb + 1][r]; o.z = t[cb + 2][r]; o.w = t[cb + 3][r];
    *(ushort4*)(out + (size_t)(c0 + r) * R + r0 + cb) = o;
}

__launch_bounds__(256)
__global__ void prep_kernel(const void* __restrict__ x, const void* __restrict__ g,
                            const void* __restrict__ bt, u16* __restrict__ xn,
                            const void* __restrict__ media, u16* __restrict__ media_c,
                            const void* __restrict__ mask, int* __restrict__ map,
                            int* __restrict__ cnt,
                            const void* __restrict__ Wq, u16* __restrict__ WqT,
                            const void* __restrict__ Wkv, u16* __restrict__ WkvT,
                            const void* __restrict__ Wout, u16* __restrict__ WoutT,
                            const unsigned* __restrict__ flags) {
    __shared__ int wsumI[4];
    __shared__ u16 t[32][33];
    bool bf = flags[0] != 0;
    int bid = blockIdx.x, tid = threadIdx.x;

    if (bid < 2048) {                        // ---- LayerNorm, two rows per wave ----
        int w = tid >> 6, lane = tid & 63;
        int row0 = (bid << 3) + (w << 1);
        float v[2][16];
        if (bf) {
            const u16* xr = (const u16*)x + (size_t)row0 * DIM;
            bf16x8 a[4];
            #pragma unroll
            for (int rr = 0; rr < 2; rr++)
                #pragma unroll
                for (int i = 0; i < 2; i++)
                    a[rr * 2 + i] = *(const bf16x8*)(xr + (size_t)rr * DIM + (lane + 64 * i) * 8);
            #pragma unroll
            for (int rr = 0; rr < 2; rr++)
                #pragma unroll
                for (int i = 0; i < 2; i++)
                    #pragma unroll
                    for (int j = 0; j < 8; j++)
                        v[rr][i * 8 + j] = b2f((u16)a[rr * 2 + i][j]);
        } else {
            const float* xr = (const float*)x + (size_t)row0 * DIM;
            float4 a[8];
            #pragma unroll
            for (int rr = 0; rr < 2; rr++)
                #pragma unroll
                for (int i = 0; i < 4; i++)
                    a[rr * 4 + i] = *(const float4*)(xr + (size_t)rr * DIM + (lane + 64 * i) * 4);
            #pragma unroll
            for (int rr = 0; rr < 2; rr++)
                #pragma unroll
                for (int i = 0; i < 4; i++) {
                    v[rr][i * 4 + 0] = a[rr * 4 + i].x; v[rr][i * 4 + 1] = a[rr * 4 + i].y;
                    v[rr][i * 4 + 2] = a[rr * 4 + i].z; v[rr][i * 4 + 3] = a[rr * 4 + i].w;
                }
        }
        float s[2] = {0.f, 0.f}, s2[2] = {0.f, 0.f};
        #pragma unroll
        for (int rr = 0; rr < 2; rr++)
            #pragma unroll
            for (int i = 0; i < 16; i++) { s[rr] += v[rr][i]; s2[rr] += v[rr][i] * v[rr][i]; }
        #pragma unroll
        for (int m = 1; m < 64; m <<= 1) {
            #pragma unroll
            for (int rr = 0; rr < 2; rr++) {
                s[rr] += __shfl_xor(s[rr], m);
                s2[rr] += __shfl_xor(s2[rr], m);
            }
        }
        float mu[2], inv[2];
        #pragma unroll
        for (int rr = 0; rr < 2; rr++) {
            mu[rr] = s[rr] * (1.f / DIM);
            float var = s2[rr] * (1.f / DIM) - mu[rr] * mu[rr];
            inv[rr] = rsqrtf(fmaxf(var, 0.f) + LN_EPS);
        }
        u16* orow = xn + (size_t)row0 * DIM;
        if (bf) {
            const u16* gr = (const u16*)g;
            const u16* br = (const u16*)bt;
            #pragma unroll
            for (int i = 0; i < 2; i++) {
                int c = (lane + 64 * i) * 8;
                bf16x8 ga = *(const bf16x8*)(gr + c);
                bf16x8 ba = *(const bf16x8*)(br + c);
                #pragma unroll
                for (int rr = 0; rr < 2; rr++) {
                    u16 o[8];
                    #pragma unroll
                    for (int j = 0; j < 8; j++)
                        o[j] = f2b((v[rr][i * 8 + j] - mu[rr]) * inv[rr] * b2f((u16)ga[j]) + b2f((u16)ba[j]));
                    *(bf16x8*)(orow + (size_t)rr * DIM + c) = *(bf16x8*)o;
                }
            }
        } else {
            const float* gr = (const float*)g;
            const float* br = (const float*)bt;
            #pragma unroll
            for (int i = 0; i < 4; i++) {
                int c = (lane + 64 * i) * 4;
                float4 ga = *(const float4*)(gr + c);
                float4 ba = *(const float4*)(br + c);
                #pragma unroll
                for (int rr = 0; rr < 2; rr++) {
                    ushort4 o;
                    o.x = f2b((v[rr][i * 4 + 0] - mu[rr]) * inv[rr] * ga.x + ba.x);
                    o.y = f2b((v[rr][i * 4 + 1] - mu[rr]) * inv[rr] * ga.y + ba.y);
                    o.z = f2b((v[rr][i * 4 + 2] - mu[rr]) * inv[rr] * ga.z + ba.z);
                    o.w = f2b((v[rr][i * 4 + 3] - mu[rr]) * inv[rr] * ga.w + ba.w);
                    *(ushort4*)(orow + (size_t)rr * DIM + c) = o;
                }
            }
        }
    } else if (bid < 4096) {                 // ---- media convert ----
        size_t i = ((size_t)(bid - 2048) * 256 + tid) * 8;
        if (bf) {
            *(bf16x8*)(media_c + i) = *(const bf16x8*)((const u16*)media + i);
        } else {
            const float* s = (const float*)media + i;
            float4 a = *(const float4*)s, b = *(const float4*)(s + 4);
            u16 o[8] = {f2b(a.x), f2b(a.y), f2b(a.z), f2b(a.w),
                        f2b(b.x), f2b(b.y), f2b(b.z), f2b(b.w)};
            *(bf16x8*)(media_c + i) = *(bf16x8*)o;
        }
    } else if (bid < 4100) {                 // ---- mask scan (one block per batch) ----
        int b = bid - 4096;
        bool bytes = flags[1] != 0;
        int v[4];
        if (bytes) {
            unsigned wd = ((const unsigned*)mask)[b * 256 + tid];
            #pragma unroll
            for (int i = 0; i < 4; i++) v[i] = ((wd >> (8 * i)) & 0xFFu) ? 1 : 0;
        } else {
            int4 m4 = ((const int4*)mask)[b * 256 + tid];
            v[0] = m4.x != 0; v[1] = m4.y != 0; v[2] = m4.z != 0; v[3] = m4.w != 0;
        }
        int tsum = v[0] + v[1] + v[2] + v[3];
        int lane = tid & 63, w = tid >> 6;
        int incl = tsum;
        #pragma unroll
        for (int off = 1; off < 64; off <<= 1) {
            int tt = __shfl_up(incl, off);
            if (lane >= off) incl += tt;
        }
        if (lane == 63) wsumI[w] = incl;
        __syncthreads();
        int base = 0;
        for (int k = 0; k < w; k++) base += wsumI[k];
        int slot = base + incl - tsum;
        int gbase = b * NLAT + tid * 4;
        #pragma unroll
        for (int i = 0; i < 4; i++) map[gbase + i] = v[i] ? slot++ : -1;
        if (tid == 0) cnt[b] = wsumI[0] + wsumI[1] + wsumI[2] + wsumI[3];
    } else if (bid < 4612) {                 // ---- Wq^T ----
        int idx = bid - 4100;
        do_transpose(Wq, WqT, DIM, INNER, idx & 15, idx >> 4, bf, t);
    } else if (bid < 5636) {                 // ---- Wkv^T ----
        int idx = bid - 4612;
        do_transpose(Wkv, WkvT, DIM, DIM, idx & 31, idx >> 5, bf, t);
    } else {                                 // ---- Wout^T ----
        int idx = bid - 5636;
        do_transpose(Wout, WoutT, INNER, DIM, idx & 31, idx >> 5, bf, t);
    }
}

// ---------------- GEMM 128x128 body, BK=64, flash-style XOR swizzle ----------------
// LDS tile [128 rows][8 groups of 8 u16]; physical group p at row r holds logical p ^ (r&7).
__device__ __forceinline__ void gemm_body(const u16* __restrict__ A, const u16* __restrict__ Bt,
                                          u16* __restrict__ C, float* __restrict__ Cf,
                                          int Ndim, int K, float scale, int mode,
                                          u16* __restrict__ vT, const int* __restrict__ map,
                                          bool outbf, int n0, int m0, u16* As, u16* Bs) {
    int tid = threadIdx.x;
    int w = tid >> 6, lane = tid & 63, quad = lane >> 4, l15 = lane & 15;
    int wm = (w >> 1) * 64, wn = (w & 1) * 64;
    f32x4 acc[4][4] = {};
    for (int k0 = 0; k0 < K; k0 += 64) {
        __syncthreads();
        #pragma unroll
        for (int i = 0; i < 4; i++) {
            int slot = i * 256 + tid;                 // slot = row*8 + physgrp
            int row = slot >> 3;
            int lg = (slot & 7) ^ (row & 7);          // logical source group
            int wbase = (i * 256 + (tid & 192)) * 8;  // wave-uniform LDS dest (u16)
            __builtin_amdgcn_global_load_lds(
                (const AS1 void*)(A + (size_t)(m0 + row) * K + k0 + lg * 8),
                (AS3 void*)(As + wbase), 16, 0, 0);
            __builtin_amdgcn_global_load_lds(
                (const AS1 void*)(Bt + (size_t)(n0 + row) * K + k0 + lg * 8),
                (AS3 void*)(Bs + wbase), 16, 0, 0);
        }
        __syncthreads();
        #pragma unroll
        for (int h = 0; h < 2; h++) {                 // two K=32 halves of the BK=64 tile
            bf16x8 af[4], bfr[4];
            #pragma unroll
            for (int i = 0; i < 4; i++) {
                int R = wm + i * 16 + l15;
                af[i] = *(bf16x8*)&As[R * 64 + (((quad + h * 4) ^ (R & 7)) * 8)];
            }
            #pragma unroll
            for (int j = 0; j < 4; j++) {
                int R = wn + j * 16 + l15;
                bfr[j] = *(bf16x8*)&Bs[R * 64 + (((quad + h * 4) ^ (R & 7)) * 8)];
            }
            #pragma unroll
            for (int i = 0; i < 4; i++)
                #pragma unroll
                for (int j = 0; j < 4; j++)
                    acc[i][j] = __builtin_amdgcn_mfma_f32_16x16x32_bf16(af[i], bfr[j], acc[i][j], 0, 0, 0);
        }
    }
    #pragma unroll
    for (int i = 0; i < 4; i++)
        #pragma unroll
        for (int j = 0; j < 4; j++)
            #pragma unroll
            for (int r = 0; r < 4; r++) {
                int row = m0 + wm + i * 16 + quad * 4 + r;
                int col = n0 + wn + j * 16 + l15;
                float val = acc[i][j][r] * scale;
                if (mode == 1) {
                    int b = row >> 10, jj = row & 1023;
                    int slot = map[(b << 10) + jj];
                    if (slot >= 0) {
                        if (col < INNER) {
                            C[((size_t)(b << 10) + slot) * INNER + col] = f2b(val);
                        } else {
                            int c = col - INNER;
                            int h = c >> 6, d = c & 63;
                            vT[(((size_t)(b * HEADS + h) * 64 + d) << 10) + slot] = f2b(val);
                        }
                    }
                } else if (outbf) {
                    C[(size_t)row * Ndim + col] = f2b(val);
                } else {
                    Cf[(size_t)row * Ndim + col] = val;
                }
            }
}

__launch_bounds__(256, 3)
__global__ void gemm128(const u16* __restrict__ A, const u16* __restrict__ Bt,
                        u16* __restrict__ C, float* __restrict__ Cf, int Ndim, int K,
                        float scale, int mode, u16* __restrict__ vT,
                        const int* __restrict__ map,
                        const unsigned* __restrict__ flags) {
    __shared__ __align__(16) u16 As[128 * 64];
    __shared__ __align__(16) u16 Bs[128 * 64];
    bool outbf = (mode != 2) || (flags[0] != 0);
    gemm_body(A, Bt, C, Cf, Ndim, K, scale, mode, vT, map, outbf,
              blockIdx.x * 128, blockIdx.y * 128, As, Bs);
}

// ---- merged Q-GEMM (512 blocks) + KV-GEMM (256 blocks): 768 blocks = 3/CU exactly ----
__launch_bounds__(256, 3)
__global__ void gemm_qkv(const u16* __restrict__ xn, const u16* __restrict__ WqT,
                         u16* __restrict__ qb,
                         const u16* __restrict__ media_c, const u16* __restrict__ WkvT,
                         u16* __restrict__ Kb, u16* __restrict__ vT,
                         const int* __restrict__ map) {
    __shared__ __align__(16) u16 As[128 * 64];
    __shared__ __align__(16) u16 Bs[128 * 64];
    int bid = blockIdx.x;
    if (bid < 512) {
        // q = LN(x) @ Wq * 1/sqrt(64) * log2(e)
        gemm_body(xn, WqT, qb, (float*)nullptr, INNER, DIM, 0.125f * 1.44269504f, 0,
                  (u16*)nullptr, (int*)nullptr, true,
                  (bid & 3) * 128, (bid >> 2) * 128, As, Bs);
    } else {
        // kv = media @ Wkv, epilogue scatters compacted K and V^T via map
        int id = bid - 512;
        gemm_body(media_c, WkvT, Kb, (float*)nullptr, DIM, DIM, 1.0f, 1,
                  vT, map, true,
                  (id & 7) * 128, (id >> 3) * 128, As, Bs);
    }
}

// ---------------- Flash attention v7: QBLK=128 (32 q-rows/wave, 2x16 groups) ----------------
// Q comes pre-scaled by 1/sqrt(64) * log2(e), so P = exp2(S).
// Swapped QK^T: S = mfma(K, Q) => lane holds P[q=l15][k = c*16 + quad*4 + r].
// Per staged KV tile each wave now does 32 MFMA (2 q-groups) -> half the barrier/stage
// overhead per unit of work vs v6; 1024 blocks = 4/CU resident.
__launch_bounds__(256, 4)
__global__ void flash_kernel(const u16* __restrict__ q, const u16* __restrict__ Kc,
                             const u16* __restrict__ vTc, const int* __restrict__ cntp,
                             u16* __restrict__ attn_out) {
    __shared__ __align__(16) u16 Ks[64 * 64];        // physical colgroup p = logical ^ (row&7)
    __shared__ __align__(16) u16 Vts[64 * 64];
    __shared__ __align__(16) u16 Ps[4][2][16 * 68];  // per-wave, per-qgroup, stride 68
    int bh = blockIdx.x >> 5;
    int qt = blockIdx.x & 31;
    int b = bh >> 3, h = bh & 7;
    int tid = threadIdx.x, w = tid >> 6, lane = tid & 63, quad = lane >> 4, l15 = lane & 15;
    int qrow0 = qt * 128 + w * 32;
    int cnt = cntp[b];

    bf16x8 qf[2][2];
    #pragma unroll
    for (int qg = 0; qg < 2; qg++) {
        size_t qbase = ((size_t)(b * NTOK) + qrow0 + qg * 16 + l15) * INNER + h * 64;
        qf[qg][0] = *(const bf16x8*)(q + qbase + quad * 8);
        qf[qg][1] = *(const bf16x8*)(q + qbase + 32 + quad * 8);
    }

    f32x4 Oacc[2][4] = {};
    float lsum[2] = {0.f, 0.f};
    int ld_row = lane >> 3;
    int ld_col = ((lane & 7) ^ ld_row) * 8;          // swizzled source colgroup

    for (int jt = 0; jt < cnt; jt += 64) {
        __syncthreads();
        #pragma unroll
        for (int i = 0; i < 2; i++) {
            int seg = w * 2 + i;                     // 8 segments = 64 rows
            int j = jt + seg * 8 + ld_row;
            __builtin_amdgcn_global_load_lds(
                (const AS1 void*)(Kc + ((size_t)(b * NLAT) + j) * INNER + h * 64 + ld_col),
                (AS3 void*)(Ks + seg * 512), 16, 0, 0);
            int d = seg * 8 + ld_row;
            __builtin_amdgcn_global_load_lds(
                (const AS1 void*)(vTc + (((size_t)(b * HEADS + h) * 64 + d) << 10) + jt + ld_col),
                (AS3 void*)(Vts + seg * 512), 16, 0, 0);
        }
        __syncthreads();

        int sw0 = (quad ^ (l15 & 7)) * 8;            // logical groups quad / quad+4
        int sw1 = ((quad + 4) ^ (l15 & 7)) * 8;
        bool full = (jt + 64 <= cnt);
        #pragma unroll
        for (int qg = 0; qg < 2; qg++) {
            f32x4 S[4];
            #pragma unroll
            for (int c = 0; c < 4; c++) {
                bf16x8 kf0 = *(bf16x8*)&Ks[(c * 16 + l15) * 64 + sw0];
                bf16x8 kf1 = *(bf16x8*)&Ks[(c * 16 + l15) * 64 + sw1];
                f32x4 s = {};
                s = __builtin_amdgcn_mfma_f32_16x16x32_bf16(kf0, qf[qg][0], s, 0, 0, 0);   // swapped
                s = __builtin_amdgcn_mfma_f32_16x16x32_bf16(kf1, qf[qg][1], s, 0, 0, 0);
                S[c] = s;
            }
            if (full) {                              // fast path: full tile, no masking
                #pragma unroll
                for (int c = 0; c < 4; c++) {
                    float p0 = exp2f(fminf(S[c][0], 115.4f));
                    float p1 = exp2f(fminf(S[c][1], 115.4f));
                    float p2 = exp2f(fminf(S[c][2], 115.4f));
                    float p3 = exp2f(fminf(S[c][3], 115.4f));
                    lsum[qg] += (p0 + p1) + (p2 + p3);
                    uint2 pw = {cvt_pk(p0, p1), cvt_pk(p2, p3)};
                    *(uint2*)&Ps[w][qg][l15 * 68 + c * 16 + quad * 4] = pw;
                }
            } else {                                 // tail tile: mask k >= cnt
                #pragma unroll
                for (int c = 0; c < 4; c++) {
                    int kbase = jt + c * 16 + quad * 4;
                    float p[4];
                    #pragma unroll
                    for (int r = 0; r < 4; r++) {
                        bool valid = (kbase + r) < cnt;
                        p[r] = valid ? exp2f(fminf(S[c][r], 115.4f)) : 0.f;
                        lsum[qg] += p[r];
                    }
                    uint2 pw = {cvt_pk(p[0], p[1]), cvt_pk(p[2], p[3])};
                    *(uint2*)&Ps[w][qg][l15 * 68 + c * 16 + quad * 4] = pw;
                }
            }
        }
        asm volatile("s_waitcnt lgkmcnt(0)" ::: "memory");   // Ps[w] is wave-private
        #pragma unroll
        for (int qg = 0; qg < 2; qg++) {
            bf16x8 pf0 = *(bf16x8*)&Ps[w][qg][l15 * 68 + quad * 8];
            bf16x8 pf1 = *(bf16x8*)&Ps[w][qg][l15 * 68 + 32 + quad * 8];
            #pragma unroll
            for (int dt = 0; dt < 4; dt++) {
                bf16x8 vf0 = *(bf16x8*)&Vts[(dt * 16 + l15) * 64 + sw0];
                bf16x8 vf1 = *(bf16x8*)&Vts[(dt * 16 + l15) * 64 + sw1];
                Oacc[qg][dt] = __builtin_amdgcn_mfma_f32_16x16x32_bf16(pf0, vf0, Oacc[qg][dt], 0, 0, 0);
                Oacc[qg][dt] = __builtin_amdgcn_mfma_f32_16x16x32_bf16(pf1, vf1, Oacc[qg][dt], 0, 0, 0);
            }
        }
    }
    // row-sum: each lane has partial for q=l15; reduce across quads, then fetch per output row
    #pragma unroll
    for (int qg = 0; qg < 2; qg++) {
        float ls = lsum[qg];
        ls += __shfl_xor(ls, 16);
        ls += __shfl_xor(ls, 32);
        #pragma unroll
        for (int r = 0; r < 4; r++) {
            float l = __shfl(ls, quad * 4 + r);      // row-sum for q row qg*16 + quad*4+r
            float invl = (l > 0.f) ? (1.f / l) : 0.f;
            #pragma unroll
            for (int dt = 0; dt < 4; dt++) {
                int row = qrow0 + qg * 16 + quad * 4 + r;
                int col = h * 64 + dt * 16 + l15;
                attn_out[(size_t)(b * NTOK + row) * INNER + col] = f2b(Oacc[qg][dt][r] * invl);
            }
        }
    }
}

extern "C" void kernel_launch(void* const* d_in, const int* in_sizes, int n_in,
                              void* d_out, int out_size, void* d_ws, size_t ws_size,
                              hipStream_t stream) {
    const void* x     = d_in[0];
    const void* media = d_in[1];
    const void* mask  = d_in[2];
    const void* g     = d_in[3];
    const void* beta  = d_in[4];
    const void* Wq    = d_in[5];
    const void* Wkv   = d_in[6];
    const void* Wout  = d_in[7];

    char* ws = (char*)d_ws;
    unsigned* flags = (unsigned*)ws;   ws += 256;
    int* map_c  = (int*)ws;            ws += (size_t)M_MED * 4;
    int* cnt_c  = (int*)ws;            ws += 256;
    u16* media_c = (u16*)ws;           ws += (size_t)M_MED * DIM * 2;
    u16* xn    = (u16*)ws;             ws += (size_t)M_X * DIM * 2;
    u16* qb    = (u16*)ws;             ws += (size_t)M_X * INNER * 2;
    u16* Kb    = (u16*)ws;             ws += (size_t)M_MED * INNER * 2;
    u16* vTb   = (u16*)ws;             ws += (size_t)M_MED * INNER * 2;
    u16* ao    = (u16*)ws;             ws += (size_t)M_X * INNER * 2;
    u16* WqT   = (u16*)ws;             ws += (size_t)DIM * INNER * 2;
    u16* WkvT  = (u16*)ws;             ws += (size_t)DIM * DIM * 2;
    u16* WoutT = (u16*)ws;             ws += (size_t)INNER * DIM * 2;

    detect_kernel<<<1, 256, 0, stream>>>((const unsigned*)x, (const unsigned*)mask, flags);
    prep_kernel<<<PREP_BLOCKS, 256, 0, stream>>>(x, g, beta, xn, media, media_c, mask, map_c, cnt_c,
                                                 Wq, WqT, Wkv, WkvT, Wout, WoutT, flags);
    // merged: q = LN(x) @ Wq * scale   AND   kv = media @ Wkv (scatter K / V^T)
    gemm_qkv<<<dim3(768), 256, 0, stream>>>(xn, WqT, qb, media_c, WkvT, Kb, vTb, map_c);
    // masked flash attention over compacted KV (QBLK=128)
    flash_kernel<<<dim3(32 * 32), 256, 0, stream>>>(qb, Kb, vTb, cnt_c, ao);
    // out = attn_out @ Wout (dtype follows flags)
    gemm128<<<dim3(DIM / 128, M_X / 128), 256, 0, stream>>>(ao, WoutT, (u16*)d_out, (float*)d_out, DIM, INNER,
                                                            1.0f, 2, (u16*)nullptr, (int*)nullptr, flags);
}

// Round 10
// 257.807 us; speedup vs baseline: 1.1391x; 1.0600x over previous
//
#include <hip/hip_runtime.h>
#include <hip/hip_bf16.h>

typedef short bf16x8 __attribute__((ext_vector_type(8)));
typedef float f32x4 __attribute__((ext_vector_type(4)));
typedef unsigned short u16;

#define AS1 __attribute__((address_space(1)))
#define AS3 __attribute__((address_space(3)))

#define DIM     1024
#define INNER   512
#define HEADS   8
#define DHEAD   64
#define BATCH   4
#define NTOK    4096
#define NLAT    1024
#define M_X     (BATCH*NTOK)    // 16384
#define M_MED   (BATCH*NLAT)    // 4096
#define LN_EPS  1e-5f

__device__ __forceinline__ float b2f(u16 h) {
    union { unsigned u; float f; } v; v.u = ((unsigned)h) << 16; return v.f;
}
__device__ __forceinline__ u16 f2b(float f) {
    union { float f; unsigned u; } v; v.f = f;
    unsigned r = v.u + 0x7fff + ((v.u >> 16) & 1);
    return (u16)(r >> 16);
}
// packed f32x2 -> bf16x2 (RNE), single instruction
__device__ __forceinline__ unsigned cvt_pk(float lo, float hi) {
    unsigned r;
    asm("v_cvt_pk_bf16_f32 %0, %1, %2" : "=v"(r) : "v"(lo), "v"(hi));
    return r;
}

// per-thread bf16-plausibility of one word of x (thread tid checks word tid; 256 words total)
__device__ __forceinline__ int word_not_bf16(unsigned w) {
    int bad = 0;
    #pragma unroll
    for (int h = 0; h < 2; h++) {
        unsigned el = (h ? (w >> 16) : w) & 0xFFFFu;
        unsigned ef = (el >> 7) & 0xFFu;
        if (!((ef >= 64u && ef < 192u) || (el & 0x7FFFu) == 0u)) bad = 1;
    }
    return bad;
}

// ---------------- fused prep (detect inlined): LN + media convert + mask scan + transposes ----------------
// region layout by blockIdx.x:
//   [0, 2048)      LN rows, 2 rows per wave (8 rows per block)
//   [2048, 4096)   media -> bf16
//   [4096, 4100)   mask scan: map[b][j] -> compact slot (-1 if masked), cnt[b]
//   [4100, 4612)   Wq^T  (16 x 32)
//   [4612, 5636)   Wkv^T (32 x 32)
//   [5636, 6148)   Wout^T(32 x 16)
#define PREP_BLOCKS 6148

__device__ __forceinline__ void do_transpose(const void* in, u16* out, int R, int C,
                                             int bx, int by, bool bf, u16 (*t)[33]) {
    int c0 = bx * 32, r0 = by * 32;
    int tid = threadIdx.x;
    int r = tid >> 3, cb = (tid & 7) * 4;
    size_t base = (size_t)(r0 + r) * C + c0 + cb;
    u16 e0, e1, e2, e3;
    if (bf) {
        ushort4 a = *(const ushort4*)((const u16*)in + base);
        e0 = a.x; e1 = a.y; e2 = a.z; e3 = a.w;
    } else {
        float4 a = *(const float4*)((const float*)in + base);
        e0 = f2b(a.x); e1 = f2b(a.y); e2 = f2b(a.z); e3 = f2b(a.w);
    }
    t[r][cb] = e0; t[r][cb + 1] = e1; t[r][cb + 2] = e2; t[r][cb + 3] = e3;
    __syncthreads();
    ushort4 o;
    o.x = t[cb + 0][r]; o.y = t[cb + 1][r]; o.z = t[cb + 2][r]; o.w = t[cb + 3][r];
    *(ushort4*)(out + (size_t)(c0 + r) * R + r0 + cb) = o;
}

__launch_bounds__(256)
__global__ void prep_kernel(const void* __restrict__ x, const void* __restrict__ g,
                            const void* __restrict__ bt, u16* __restrict__ xn,
                            const void* __restrict__ media, u16* __restrict__ media_c,
                            const void* __restrict__ mask, int* __restrict__ map,
                            int* __restrict__ cnt,
                            const void* __restrict__ Wq, u16* __restrict__ WqT,
                            const void* __restrict__ Wkv, u16* __restrict__ WkvT,
                            const void* __restrict__ Wout, u16* __restrict__ WoutT) {
    __shared__ int wsumI[4];
    __shared__ u16 t[32][33];
    __shared__ int s_bad, s_byte;
    int bid = blockIdx.x, tid = threadIdx.x;

    // ---- inline dtype detect (replaces detect_kernel): every block derives bf itself ----
    if (tid == 0) { s_bad = 0; s_byte = 0; }
    __syncthreads();
    {
        int bad = word_not_bf16(((const unsigned*)x)[tid]);
        int byte = 0;
        if (bid >= 4096 && bid < 4100) {             // mask-scan blocks also derive byte-mask flag
            const unsigned* mw = (const unsigned*)mask;
            for (int i = tid; i < NLAT; i += 256)
                if (mw[i] > 1u) { byte = 1; break; }
        }
        if (bad) atomicOr(&s_bad, 1);
        if (byte) atomicOr(&s_byte, 1);
    }
    __syncthreads();
    bool bf = (s_bad == 0);

    if (bid < 2048) {                        // ---- LayerNorm, two rows per wave ----
        int w = tid >> 6, lane = tid & 63;
        int row0 = (bid << 3) + (w << 1);
        float v[2][16];
        if (bf) {
            const u16* xr = (const u16*)x + (size_t)row0 * DIM;
            bf16x8 a[4];
            #pragma unroll
            for (int rr = 0; rr < 2; rr++)
                #pragma unroll
                for (int i = 0; i < 2; i++)
                    a[rr * 2 + i] = *(const bf16x8*)(xr + (size_t)rr * DIM + (lane + 64 * i) * 8);
            #pragma unroll
            for (int rr = 0; rr < 2; rr++)
                #pragma unroll
                for (int i = 0; i < 2; i++)
                    #pragma unroll
                    for (int j = 0; j < 8; j++)
                        v[rr][i * 8 + j] = b2f((u16)a[rr * 2 + i][j]);
        } else {
            const float* xr = (const float*)x + (size_t)row0 * DIM;
            float4 a[8];
            #pragma unroll
            for (int rr = 0; rr < 2; rr++)
                #pragma unroll
                for (int i = 0; i < 4; i++)
                    a[rr * 4 + i] = *(const float4*)(xr + (size_t)rr * DIM + (lane + 64 * i) * 4);
            #pragma unroll
            for (int rr = 0; rr < 2; rr++)
                #pragma unroll
                for (int i = 0; i < 4; i++) {
                    v[rr][i * 4 + 0] = a[rr * 4 + i].x; v[rr][i * 4 + 1] = a[rr * 4 + i].y;
                    v[rr][i * 4 + 2] = a[rr * 4 + i].z; v[rr][i * 4 + 3] = a[rr * 4 + i].w;
                }
        }
        float s[2] = {0.f, 0.f}, s2[2] = {0.f, 0.f};
        #pragma unroll
        for (int rr = 0; rr < 2; rr++)
            #pragma unroll
            for (int i = 0; i < 16; i++) { s[rr] += v[rr][i]; s2[rr] += v[rr][i] * v[rr][i]; }
        #pragma unroll
        for (int m = 1; m < 64; m <<= 1) {
            #pragma unroll
            for (int rr = 0; rr < 2; rr++) {
                s[rr] += __shfl_xor(s[rr], m);
                s2[rr] += __shfl_xor(s2[rr], m);
            }
        }
        float mu[2], inv[2];
        #pragma unroll
        for (int rr = 0; rr < 2; rr++) {
            mu[rr] = s[rr] * (1.f / DIM);
            float var = s2[rr] * (1.f / DIM) - mu[rr] * mu[rr];
            inv[rr] = rsqrtf(fmaxf(var, 0.f) + LN_EPS);
        }
        u16* orow = xn + (size_t)row0 * DIM;
        if (bf) {
            const u16* gr = (const u16*)g;
            const u16* br = (const u16*)bt;
            #pragma unroll
            for (int i = 0; i < 2; i++) {
                int c = (lane + 64 * i) * 8;
                bf16x8 ga = *(const bf16x8*)(gr + c);
                bf16x8 ba = *(const bf16x8*)(br + c);
                #pragma unroll
                for (int rr = 0; rr < 2; rr++) {
                    u16 o[8];
                    #pragma unroll
                    for (int j = 0; j < 8; j++)
                        o[j] = f2b((v[rr][i * 8 + j] - mu[rr]) * inv[rr] * b2f((u16)ga[j]) + b2f((u16)ba[j]));
                    *(bf16x8*)(orow + (size_t)rr * DIM + c) = *(bf16x8*)o;
                }
            }
        } else {
            const float* gr = (const float*)g;
            const float* br = (const float*)bt;
            #pragma unroll
            for (int i = 0; i < 4; i++) {
                int c = (lane + 64 * i) * 4;
                float4 ga = *(const float4*)(gr + c);
                float4 ba = *(const float4*)(br + c);
                #pragma unroll
                for (int rr = 0; rr < 2; rr++) {
                    ushort4 o;
                    o.x = f2b((v[rr][i * 4 + 0] - mu[rr]) * inv[rr] * ga.x + ba.x);
                    o.y = f2b((v[rr][i * 4 + 1] - mu[rr]) * inv[rr] * ga.y + ba.y);
                    o.z = f2b((v[rr][i * 4 + 2] - mu[rr]) * inv[rr] * ga.z + ba.z);
                    o.w = f2b((v[rr][i * 4 + 3] - mu[rr]) * inv[rr] * ga.w + ba.w);
                    *(ushort4*)(orow + (size_t)rr * DIM + c) = o;
                }
            }
        }
    } else if (bid < 4096) {                 // ---- media convert ----
        size_t i = ((size_t)(bid - 2048) * 256 + tid) * 8;
        if (bf) {
            *(bf16x8*)(media_c + i) = *(const bf16x8*)((const u16*)media + i);
        } else {
            const float* s = (const float*)media + i;
            float4 a = *(const float4*)s, b = *(const float4*)(s + 4);
            u16 o[8] = {f2b(a.x), f2b(a.y), f2b(a.z), f2b(a.w),
                        f2b(b.x), f2b(b.y), f2b(b.z), f2b(b.w)};
            *(bf16x8*)(media_c + i) = *(bf16x8*)o;
        }
    } else if (bid < 4100) {                 // ---- mask scan (one block per batch) ----
        int b = bid - 4096;
        bool bytes = (s_byte != 0);
        int v[4];
        if (bytes) {
            unsigned wd = ((const unsigned*)mask)[b * 256 + tid];
            #pragma unroll
            for (int i = 0; i < 4; i++) v[i] = ((wd >> (8 * i)) & 0xFFu) ? 1 : 0;
        } else {
            int4 m4 = ((const int4*)mask)[b * 256 + tid];
            v[0] = m4.x != 0; v[1] = m4.y != 0; v[2] = m4.z != 0; v[3] = m4.w != 0;
        }
        int tsum = v[0] + v[1] + v[2] + v[3];
        int lane = tid & 63, w = tid >> 6;
        int incl = tsum;
        #pragma unroll
        for (int off = 1; off < 64; off <<= 1) {
            int tt = __shfl_up(incl, off);
            if (lane >= off) incl += tt;
        }
        if (lane == 63) wsumI[w] = incl;
        __syncthreads();
        int base = 0;
        for (int k = 0; k < w; k++) base += wsumI[k];
        int slot = base + incl - tsum;
        int gbase = b * NLAT + tid * 4;
        #pragma unroll
        for (int i = 0; i < 4; i++) map[gbase + i] = v[i] ? slot++ : -1;
        if (tid == 0) cnt[b] = wsumI[0] + wsumI[1] + wsumI[2] + wsumI[3];
    } else if (bid < 4612) {                 // ---- Wq^T ----
        int idx = bid - 4100;
        do_transpose(Wq, WqT, DIM, INNER, idx & 15, idx >> 4, bf, t);
    } else if (bid < 5636) {                 // ---- Wkv^T ----
        int idx = bid - 4612;
        do_transpose(Wkv, WkvT, DIM, DIM, idx & 31, idx >> 5, bf, t);
    } else {                                 // ---- Wout^T ----
        int idx = bid - 5636;
        do_transpose(Wout, WoutT, INNER, DIM, idx & 31, idx >> 5, bf, t);
    }
}

// ---------------- GEMM 128x128 body, BK=64, flash-style XOR swizzle ----------------
// LDS tile [128 rows][8 groups of 8 u16]; physical group p at row r holds logical p ^ (r&7).
__device__ __forceinline__ void gemm_body(const u16* __restrict__ A, const u16* __restrict__ Bt,
                                          u16* __restrict__ C, float* __restrict__ Cf,
                                          int Ndim, int K, float scale, int mode,
                                          u16* __restrict__ vT, const int* __restrict__ map,
                                          bool outbf, int n0, int m0, u16* As, u16* Bs) {
    int tid = threadIdx.x;
    int w = tid >> 6, lane = tid & 63, quad = lane >> 4, l15 = lane & 15;
    int wm = (w >> 1) * 64, wn = (w & 1) * 64;
    f32x4 acc[4][4] = {};
    for (int k0 = 0; k0 < K; k0 += 64) {
        __syncthreads();
        #pragma unroll
        for (int i = 0; i < 4; i++) {
            int slot = i * 256 + tid;                 // slot = row*8 + physgrp
            int row = slot >> 3;
            int lg = (slot & 7) ^ (row & 7);          // logical source group
            int wbase = (i * 256 + (tid & 192)) * 8;  // wave-uniform LDS dest (u16)
            __builtin_amdgcn_global_load_lds(
                (const AS1 void*)(A + (size_t)(m0 + row) * K + k0 + lg * 8),
                (AS3 void*)(As + wbase), 16, 0, 0);
            __builtin_amdgcn_global_load_lds(
                (const AS1 void*)(Bt + (size_t)(n0 + row) * K + k0 + lg * 8),
                (AS3 void*)(Bs + wbase), 16, 0, 0);
        }
        __syncthreads();
        #pragma unroll
        for (int h = 0; h < 2; h++) {                 // two K=32 halves of the BK=64 tile
            bf16x8 af[4], bfr[4];
            #pragma unroll
            for (int i = 0; i < 4; i++) {
                int R = wm + i * 16 + l15;
                af[i] = *(bf16x8*)&As[R * 64 + (((quad + h * 4) ^ (R & 7)) * 8)];
            }
            #pragma unroll
            for (int j = 0; j < 4; j++) {
                int R = wn + j * 16 + l15;
                bfr[j] = *(bf16x8*)&Bs[R * 64 + (((quad + h * 4) ^ (R & 7)) * 8)];
            }
            #pragma unroll
            for (int i = 0; i < 4; i++)
                #pragma unroll
                for (int j = 0; j < 4; j++)
                    acc[i][j] = __builtin_amdgcn_mfma_f32_16x16x32_bf16(af[i], bfr[j], acc[i][j], 0, 0, 0);
        }
    }
    #pragma unroll
    for (int i = 0; i < 4; i++)
        #pragma unroll
        for (int j = 0; j < 4; j++)
            #pragma unroll
            for (int r = 0; r < 4; r++) {
                int row = m0 + wm + i * 16 + quad * 4 + r;
                int col = n0 + wn + j * 16 + l15;
                float val = acc[i][j][r] * scale;
                if (mode == 1) {
                    int b = row >> 10, jj = row & 1023;
                    int slot = map[(b << 10) + jj];
                    if (slot >= 0) {
                        if (col < INNER) {
                            C[((size_t)(b << 10) + slot) * INNER + col] = f2b(val);
                        } else {
                            int c = col - INNER;
                            int h = c >> 6, d = c & 63;
                            vT[(((size_t)(b * HEADS + h) * 64 + d) << 10) + slot] = f2b(val);
                        }
                    }
                } else if (outbf) {
                    C[(size_t)row * Ndim + col] = f2b(val);
                } else {
                    Cf[(size_t)row * Ndim + col] = val;
                }
            }
}

// out-GEMM: detects output dtype itself from x (no extra barrier: K-loop barriers order s_bad)
__launch_bounds__(256, 3)
__global__ void gemm128(const u16* __restrict__ A, const u16* __restrict__ Bt,
                        u16* __restrict__ C, float* __restrict__ Cf, int Ndim, int K,
                        float scale, int mode, u16* __restrict__ vT,
                        const int* __restrict__ map,
                        const unsigned* __restrict__ xw) {
    __shared__ __align__(16) u16 As[128 * 64];
    __shared__ __align__(16) u16 Bs[128 * 64];
    __shared__ int s_bad;
    if (threadIdx.x == 0) s_bad = 0;
    __syncthreads();
    if (word_not_bf16(xw[threadIdx.x])) atomicOr(&s_bad, 1);
    // s_bad is read only in the epilogue; the K-loop's barriers guarantee visibility.
    gemm_body(A, Bt, C, Cf, Ndim, K, scale, mode, vT, map, /*outbf placeholder*/ false,
              blockIdx.x * 128, blockIdx.y * 128, As, Bs);
    // NOTE: gemm_body handles outbf inline; for mode 2 we re-dispatch the epilogue below.
}

// Separate body instantiation for the out-GEMM so outbf can come from s_bad after the loop.
__launch_bounds__(256, 3)
__global__ void gemm_out(const u16* __restrict__ A, const u16* __restrict__ Bt,
                         u16* __restrict__ C, float* __restrict__ Cf,
                         const unsigned* __restrict__ xw) {
    __shared__ __align__(16) u16 As[128 * 64];
    __shared__ __align__(16) u16 Bs[128 * 64];
    __shared__ int s_bad;
    if (threadIdx.x == 0) s_bad = 0;
    __syncthreads();
    if (word_not_bf16(xw[threadIdx.x])) atomicOr(&s_bad, 1);

    const int Ndim = DIM, K = INNER;
    int n0 = blockIdx.x * 128, m0 = blockIdx.y * 128;
    int tid = threadIdx.x;
    int w = tid >> 6, lane = tid & 63, quad = lane >> 4, l15 = lane & 15;
    int wm = (w >> 1) * 64, wn = (w & 1) * 64;
    f32x4 acc[4][4] = {};
    for (int k0 = 0; k0 < K; k0 += 64) {
        __syncthreads();
        #pragma unroll
        for (int i = 0; i < 4; i++) {
            int slot = i * 256 + tid;
            int row = slot >> 3;
            int lg = (slot & 7) ^ (row & 7);
            int wbase = (i * 256 + (tid & 192)) * 8;
            __builtin_amdgcn_global_load_lds(
                (const AS1 void*)(A + (size_t)(m0 + row) * K + k0 + lg * 8),
                (AS3 void*)(As + wbase), 16, 0, 0);
            __builtin_amdgcn_global_load_lds(
                (const AS1 void*)(Bt + (size_t)(n0 + row) * K + k0 + lg * 8),
                (AS3 void*)(Bs + wbase), 16, 0, 0);
        }
        __syncthreads();
        #pragma unroll
        for (int h = 0; h < 2; h++) {
            bf16x8 af[4], bfr[4];
            #pragma unroll
            for (int i = 0; i < 4; i++) {
                int R = wm + i * 16 + l15;
                af[i] = *(bf16x8*)&As[R * 64 + (((quad + h * 4) ^ (R & 7)) * 8)];
            }
            #pragma unroll
            for (int j = 0; j < 4; j++) {
                int R = wn + j * 16 + l15;
                bfr[j] = *(bf16x8*)&Bs[R * 64 + (((quad + h * 4) ^ (R & 7)) * 8)];
            }
            #pragma unroll
            for (int i = 0; i < 4; i++)
                #pragma unroll
                for (int j = 0; j < 4; j++)
                    acc[i][j] = __builtin_amdgcn_mfma_f32_16x16x32_bf16(af[i], bfr[j], acc[i][j], 0, 0, 0);
        }
    }
    bool outbf = (s_bad == 0);               // ordered by the K-loop barriers above
    #pragma unroll
    for (int i = 0; i < 4; i++)
        #pragma unroll
        for (int j = 0; j < 4; j++)
            #pragma unroll
            for (int r = 0; r < 4; r++) {
                int row = m0 + wm + i * 16 + quad * 4 + r;
                int col = n0 + wn + j * 16 + l15;
                float val = acc[i][j][r];
                if (outbf) C[(size_t)row * Ndim + col] = f2b(val);
                else       Cf[(size_t)row * Ndim + col] = val;
            }
}

// ---- merged Q-GEMM (512 blocks) + KV-GEMM (256 blocks): 768 blocks = 3/CU exactly ----
__launch_bounds__(256, 3)
__global__ void gemm_qkv(const u16* __restrict__ xn, const u16* __restrict__ WqT,
                         u16* __restrict__ qb,
                         const u16* __restrict__ media_c, const u16* __restrict__ WkvT,
                         u16* __restrict__ Kb, u16* __restrict__ vT,
                         const int* __restrict__ map) {
    __shared__ __align__(16) u16 As[128 * 64];
    __shared__ __align__(16) u16 Bs[128 * 64];
    int bid = blockIdx.x;
    if (bid < 512) {
        // q = LN(x) @ Wq * 1/sqrt(64) * log2(e)
        gemm_body(xn, WqT, qb, (float*)nullptr, INNER, DIM, 0.125f * 1.44269504f, 0,
                  (u16*)nullptr, (int*)nullptr, true,
                  (bid & 3) * 128, (bid >> 2) * 128, As, Bs);
    } else {
        // kv = media @ Wkv, epilogue scatters compacted K and V^T via map
        int id = bid - 512;
        gemm_body(media_c, WkvT, Kb, (float*)nullptr, DIM, DIM, 1.0f, 1,
                  vT, map, true,
                  (id & 7) * 128, (id >> 3) * 128, As, Bs);
    }
}

// ---------------- Flash attention v6: swapped QK^T, packed P, exp2 ----------------
// Q comes pre-scaled by 1/sqrt(64) * log2(e), so P = exp2(S).
// Swapped QK^T: S = mfma(K, Q) => lane holds P[q=l15][k = c*16 + quad*4 + r]
// (4 consecutive k per lane -> cvt_pk + ds_write_b64 packing, no cross-lane).
__launch_bounds__(256, 6)
__global__ void flash_kernel(const u16* __restrict__ q, const u16* __restrict__ Kc,
                             const u16* __restrict__ vTc, const int* __restrict__ cntp,
                             u16* __restrict__ attn_out) {
    __shared__ __align__(16) u16 Ks[64 * 64];        // physical colgroup p = logical ^ (row&7)
    __shared__ __align__(16) u16 Vts[64 * 64];
    __shared__ __align__(16) u16 Ps[4][16 * 68];     // per-wave, q-major stride 68
    int bh = blockIdx.x >> 6;
    int qt = blockIdx.x & 63;
    int b = bh >> 3, h = bh & 7;
    int tid = threadIdx.x, w = tid >> 6, lane = tid & 63, quad = lane >> 4, l15 = lane & 15;
    int qrow0 = qt * 64 + w * 16;
    int cnt = cntp[b];

    size_t qbase = ((size_t)(b * NTOK) + qrow0 + l15) * INNER + h * 64;
    bf16x8 qf[2];
    qf[0] = *(const bf16x8*)(q + qbase + quad * 8);
    qf[1] = *(const bf16x8*)(q + qbase + 32 + quad * 8);

    f32x4 Oacc[4] = {};
    float lsum = 0.f;
    int ld_row = lane >> 3;
    int ld_col = ((lane & 7) ^ ld_row) * 8;          // swizzled source colgroup

    for (int jt = 0; jt < cnt; jt += 64) {
        __syncthreads();
        #pragma unroll
        for (int i = 0; i < 2; i++) {
            int seg = w * 2 + i;                     // 8 segments = 64 rows
            int j = jt + seg * 8 + ld_row;
            __builtin_amdgcn_global_load_lds(
                (const AS1 void*)(Kc + ((size_t)(b * NLAT) + j) * INNER + h * 64 + ld_col),
                (AS3 void*)(Ks + seg * 512), 16, 0, 0);
            int d = seg * 8 + ld_row;
            __builtin_amdgcn_global_load_lds(
                (const AS1 void*)(vTc + (((size_t)(b * HEADS + h) * 64 + d) << 10) + jt + ld_col),
                (AS3 void*)(Vts + seg * 512), 16, 0, 0);
        }
        __syncthreads();

        int sw0 = (quad ^ (l15 & 7)) * 8;            // logical groups quad / quad+4
        int sw1 = ((quad + 4) ^ (l15 & 7)) * 8;
        f32x4 S[4];
        #pragma unroll
        for (int c = 0; c < 4; c++) {
            bf16x8 kf0 = *(bf16x8*)&Ks[(c * 16 + l15) * 64 + sw0];
            bf16x8 kf1 = *(bf16x8*)&Ks[(c * 16 + l15) * 64 + sw1];
            f32x4 s = {};
            s = __builtin_amdgcn_mfma_f32_16x16x32_bf16(kf0, qf[0], s, 0, 0, 0);   // swapped
            s = __builtin_amdgcn_mfma_f32_16x16x32_bf16(kf1, qf[1], s, 0, 0, 0);
            S[c] = s;
        }
        if (jt + 64 <= cnt) {                        // fast path: full tile, no masking
            #pragma unroll
            for (int c = 0; c < 4; c++) {
                float p0 = exp2f(fminf(S[c][0], 115.4f));
                float p1 = exp2f(fminf(S[c][1], 115.4f));
                float p2 = exp2f(fminf(S[c][2], 115.4f));
                float p3 = exp2f(fminf(S[c][3], 115.4f));
                lsum += (p0 + p1) + (p2 + p3);
                uint2 pw = {cvt_pk(p0, p1), cvt_pk(p2, p3)};
                *(uint2*)&Ps[w][l15 * 68 + c * 16 + quad * 4] = pw;
            }
        } else {                                     // tail tile: mask k >= cnt
            #pragma unroll
            for (int c = 0; c < 4; c++) {
                int kbase = jt + c * 16 + quad * 4;
                float p[4];
                #pragma unroll
                for (int r = 0; r < 4; r++) {
                    bool valid = (kbase + r) < cnt;
                    p[r] = valid ? exp2f(fminf(S[c][r], 115.4f)) : 0.f;
                    lsum += p[r];
                }
                uint2 pw = {cvt_pk(p[0], p[1]), cvt_pk(p[2], p[3])};
                *(uint2*)&Ps[w][l15 * 68 + c * 16 + quad * 4] = pw;
            }
        }
        asm volatile("s_waitcnt lgkmcnt(0)" ::: "memory");   // Ps[w] is wave-private
        bf16x8 pf0 = *(bf16x8*)&Ps[w][l15 * 68 + quad * 8];
        bf16x8 pf1 = *(bf16x8*)&Ps[w][l15 * 68 + 32 + quad * 8];
        #pragma unroll
        for (int dt = 0; dt < 4; dt++) {
            bf16x8 vf0 = *(bf16x8*)&Vts[(dt * 16 + l15) * 64 + sw0];
            bf16x8 vf1 = *(bf16x8*)&Vts[(dt * 16 + l15) * 64 + sw1];
            Oacc[dt] = __builtin_amdgcn_mfma_f32_16x16x32_bf16(pf0, vf0, Oacc[dt], 0, 0, 0);
            Oacc[dt] = __builtin_amdgcn_mfma_f32_16x16x32_bf16(pf1, vf1, Oacc[dt], 0, 0, 0);
        }
    }
    // row-sum: each lane has partial for q=l15; reduce across quads, then fetch per output row
    lsum += __shfl_xor(lsum, 16);
    lsum += __shfl_xor(lsum, 32);
    #pragma unroll
    for (int r = 0; r < 4; r++) {
        float l = __shfl(lsum, quad * 4 + r);        // row-sum for q row quad*4+r
        float invl = (l > 0.f) ? (1.f / l) : 0.f;
        #pragma unroll
        for (int dt = 0; dt < 4; dt++) {
            int row = qrow0 + quad * 4 + r;
            int col = h * 64 + dt * 16 + l15;
            attn_out[(size_t)(b * NTOK + row) * INNER + col] = f2b(Oacc[dt][r] * invl);
        }
    }
}

extern "C" void kernel_launch(void* const* d_in, const int* in_sizes, int n_in,
                              void* d_out, int out_size, void* d_ws, size_t ws_size,
                              hipStream_t stream) {
    const void* x     = d_in[0];
    const void* media = d_in[1];
    const void* mask  = d_in[2];
    const void* g     = d_in[3];
    const void* beta  = d_in[4];
    const void* Wq    = d_in[5];
    const void* Wkv   = d_in[6];
    const void* Wout  = d_in[7];

    char* ws = (char*)d_ws;
    int* map_c  = (int*)ws;            ws += (size_t)M_MED * 4;
    int* cnt_c  = (int*)ws;            ws += 256;
    u16* media_c = (u16*)ws;           ws += (size_t)M_MED * DIM * 2;
    u16* xn    = (u16*)ws;             ws += (size_t)M_X * DIM * 2;
    u16* qb    = (u16*)ws;             ws += (size_t)M_X * INNER * 2;
    u16* Kb    = (u16*)ws;             ws += (size_t)M_MED * INNER * 2;
    u16* vTb   = (u16*)ws;             ws += (size_t)M_MED * INNER * 2;
    u16* ao    = (u16*)ws;             ws += (size_t)M_X * INNER * 2;
    u16* WqT   = (u16*)ws;             ws += (size_t)DIM * INNER * 2;
    u16* WkvT  = (u16*)ws;             ws += (size_t)DIM * DIM * 2;
    u16* WoutT = (u16*)ws;             ws += (size_t)INNER * DIM * 2;

    // prep (detect inlined): LN + media + mask scan + weight transposes
    prep_kernel<<<PREP_BLOCKS, 256, 0, stream>>>(x, g, beta, xn, media, media_c, mask, map_c, cnt_c,
                                                 Wq, WqT, Wkv, WkvT, Wout, WoutT);
    // merged: q = LN(x) @ Wq * scale   AND   kv = media @ Wkv (scatter K / V^T)
    gemm_qkv<<<dim3(768), 256, 0, stream>>>(xn, WqT, qb, media_c, WkvT, Kb, vTb, map_c);
    // masked flash attention over compacted KV
    flash_kernel<<<dim3(32 * 64), 256, 0, stream>>>(qb, Kb, vTb, cnt_c, ao);
    // out = attn_out @ Wout (output dtype detected in-kernel from x)
    gemm_out<<<dim3(DIM / 128, M_X / 128), 256, 0, stream>>>(ao, WoutT, (u16*)d_out, (float*)d_out,
                                                             (const unsigned*)x);
}